// Round 2
// baseline (2574.580 us; speedup 1.0000x reference)
//
#include <hip/hip_runtime.h>
#include <hip/hip_bf16.h>
#include <math.h>

#define BATCH 8
#define CIN   16
#define DDEP  8      // conv spatial depth (routing "D")
#define HIN   96
#define WIN   96
#define HOUT  94
#define WOUT  94
#define HW    (HOUT*WOUT)        // 8836
#define CH    256                 // conv out channels = c*8+d
#define DCAP  8
#define EPSQ  1e-8f

#define B_ELEMS ((size_t)BATCH*DDEP*DCAP*HW)   // 4,524,032 floats = 18.1 MB
#define U_ELEMS ((size_t)BATCH*HW*DDEP*CH)     // 144,769,024 elems

// ---------- u storage helpers (float or bf16-as-ushort) ----------
__device__ __forceinline__ float u_ld(const ushort* p){ return __bfloat162float(*(const __hip_bfloat16*)p); }
__device__ __forceinline__ float u_ld(const float*  p){ return *p; }
__device__ __forceinline__ void  u_st(ushort* p, float v){ *(__hip_bfloat16*)p = __float2bfloat16(v); }
__device__ __forceinline__ void  u_st(float*  p, float v){ *p = v; }

// ---------- conv core: 2x2 (h,w) tile, all D, one thread per out channel ----
// NOTE: contains one __syncthreads() (uniform for all threads).
__device__ __forceinline__ void conv_core(
    const float* __restrict__ x, const float* __restrict__ wconv,
    float (*patch)[DDEP][4][4], int bb, int h0, int w0, int t,
    float acc[DDEP][4])
{
    // stage x patch: 16*8*4*4 = 2048 floats
    #pragma unroll
    for (int k = 0; k < 8; ++k) {
        int i  = t + 256 * k;
        int ci = i >> 7, rem = i & 127;
        int D  = rem >> 4, y = (rem >> 2) & 3, xx = rem & 3;
        patch[ci][D][y][xx] =
            x[(((size_t)(bb * CIN + ci) * DDEP + D) * HIN + (h0 + y)) * WIN + (w0 + xx)];
    }
    __syncthreads();

    #pragma unroll
    for (int D = 0; D < DDEP; ++D)
        #pragma unroll
        for (int s = 0; s < 4; ++s) acc[D][s] = 0.f;

    const float* wp = wconv + (size_t)t * (CIN * 9);
    for (int ci = 0; ci < CIN; ++ci) {
        float wg[9];
        #pragma unroll
        for (int j = 0; j < 9; ++j) wg[j] = wp[ci * 9 + j];
        #pragma unroll
        for (int D = 0; D < DDEP; ++D) {
            const float* pr = &patch[ci][D][0][0];
            float4 r0 = ((const float4*)pr)[0];
            float4 r1 = ((const float4*)pr)[1];
            float4 r2 = ((const float4*)pr)[2];
            float4 r3 = ((const float4*)pr)[3];
            float rr[4][4] = {
                {r0.x,r0.y,r0.z,r0.w},{r1.x,r1.y,r1.z,r1.w},
                {r2.x,r2.y,r2.z,r2.w},{r3.x,r3.y,r3.z,r3.w}};
            #pragma unroll
            for (int sy = 0; sy < 2; ++sy)
                #pragma unroll
                for (int sx = 0; sx < 2; ++sx) {
                    float a = acc[D][sy*2+sx];
                    #pragma unroll
                    for (int kh = 0; kh < 3; ++kh)
                        #pragma unroll
                        for (int kw = 0; kw < 3; ++kw)
                            a += rr[sy+kh][sx+kw] * wg[kh*3+kw];
                    acc[D][sy*2+sx] = a;
                }
        }
    }
}

// ---------------------------------------------------------------------------
// Kernel: conv + routing iteration 1 (c uniform = 1/70688). Optionally writes
// u (layout [site][D][ch]) in storage type UT. Writes b1.
// ---------------------------------------------------------------------------
template<typename UT, bool STOREU>
__global__ __launch_bounds__(256) void conv_iter1(
    const float* __restrict__ x, const float* __restrict__ wconv,
    UT* __restrict__ u, float* __restrict__ bws)
{
    const int t  = threadIdx.x;
    const int wx = blockIdx.x, hy = blockIdx.y, bb = blockIdx.z;
    const int h0 = hy * 2, w0 = wx * 2;

    __shared__ float patch[CIN][DDEP][4][4];   // 8 KB
    __shared__ float n2s[4][8][4];             // [wave][d][site]
    __shared__ float dbs[4][8][8][4];          // [wave][D][d][site]

    float acc[DDEP][4];
    conv_core(x, wconv, patch, bb, h0, w0, t, acc);

    const int ch = t;
    if (STOREU) {
        #pragma unroll
        for (int sy = 0; sy < 2; ++sy)
            #pragma unroll
            for (int sx = 0; sx < 2; ++sx) {
                size_t site = (size_t)bb * HW + (size_t)(h0+sy) * WOUT + (w0+sx);
                UT* up = u + site * (DDEP * CH);
                #pragma unroll
                for (int D = 0; D < DDEP; ++D) u_st(&up[D*CH + ch], acc[D][sy*2+sx]);
            }
    }

    const int d = ch & 7;
    const int lane = t & 63, wv = t >> 6;
    const float inv = 1.0f / (float)(DCAP * HW);

    float s1[4], v[4];
    #pragma unroll
    for (int s = 0; s < 4; ++s) {
        float sum = 0.f;
        #pragma unroll
        for (int D = 0; D < DDEP; ++D) sum += acc[D][s];
        s1[s] = sum * inv;
    }
    float p[4];
    #pragma unroll
    for (int s = 0; s < 4; ++s) p[s] = s1[s] * s1[s];
    #pragma unroll
    for (int off = 8; off < 64; off <<= 1)
        #pragma unroll
        for (int s = 0; s < 4; ++s) p[s] += __shfl_xor(p[s], off);
    if (lane < 8)
        #pragma unroll
        for (int s = 0; s < 4; ++s) n2s[wv][lane][s] = p[s];
    __syncthreads();
    #pragma unroll
    for (int s = 0; s < 4; ++s) {
        float n2 = n2s[0][d][s] + n2s[1][d][s] + n2s[2][d][s] + n2s[3][d][s];
        v[s] = s1[s] * (n2 / (1.f + n2)) / sqrtf(n2 + EPSQ);
    }
    #pragma unroll
    for (int D = 0; D < DDEP; ++D) {
        float q[4];
        #pragma unroll
        for (int s = 0; s < 4; ++s) q[s] = acc[D][s] * v[s];
        #pragma unroll
        for (int off = 8; off < 64; off <<= 1)
            #pragma unroll
            for (int s = 0; s < 4; ++s) q[s] += __shfl_xor(q[s], off);
        if (lane < 8)
            #pragma unroll
            for (int s = 0; s < 4; ++s) dbs[wv][D][lane][s] = q[s];
    }
    __syncthreads();
    {
        int D = t >> 5, d2 = (t >> 2) & 7, s = t & 3;
        int sy = s >> 1, sx = s & 1;
        float db = dbs[0][D][d2][s] + dbs[1][D][d2][s] + dbs[2][D][d2][s] + dbs[3][D][d2][s];
        bws[((size_t)(bb*DDEP + D)*DCAP + d2)*HW + (size_t)(h0+sy)*WOUT + (w0+sx)] = db;
    }
}

// ---------------------------------------------------------------------------
// Z[B,D] = sum over (d,h,w) of exp(b). 64 blocks, one per (B,D).
// ---------------------------------------------------------------------------
__global__ __launch_bounds__(256) void softmax_z(
    const float* __restrict__ bws, float* __restrict__ Z)
{
    const int bd = blockIdx.x;
    const float* p = bws + (size_t)bd * (DCAP * HW);
    float sum = 0.f;
    for (int i = threadIdx.x; i < DCAP * HW; i += 256) sum += expf(p[i]);
    #pragma unroll
    for (int off = 1; off < 64; off <<= 1) sum += __shfl_xor(sum, off);
    __shared__ float ps[4];
    if ((threadIdx.x & 63) == 0) ps[threadIdx.x >> 6] = sum;
    __syncthreads();
    if (threadIdx.x == 0) Z[bd] = ps[0] + ps[1] + ps[2] + ps[3];
}

// ---------------------------------------------------------------------------
// Path A iteration 2: one pass over stored u, b += db in place.
// ---------------------------------------------------------------------------
template<typename UT>
__global__ __launch_bounds__(256) void route_iter(
    const UT* __restrict__ u, float* __restrict__ bws, const float* __restrict__ Z)
{
    const int t = threadIdx.x, lane = t & 63, wv = t >> 6;
    const int wc = blockIdx.x, h = blockIdx.y, bb = blockIdx.z;
    const int w0 = wc * 47;

    __shared__ float brow[64][47];
    __shared__ float cm[64];
    __shared__ float n2s[4][8];
    __shared__ float dbs[4][8][8];
    __shared__ float invZ[8];

    if (t < 8) invZ[t] = 1.0f / Z[bb * 8 + t];
    for (int i = t; i < 64 * 47; i += 256) {
        int pl = i / 47, wi = i - pl * 47;
        brow[pl][wi] = bws[((size_t)bb*64 + pl)*HW + (size_t)h*WOUT + (w0+wi)];
    }
    __syncthreads();

    const int ch = t, d = ch & 7;
    for (int si = 0; si < 47; ++si) {
        if (t < 64) cm[t] = expf(brow[t][si]) * invZ[t >> 3];
        __syncthreads();

        size_t site = (size_t)bb * HW + (size_t)h * WOUT + (w0 + si);
        const UT* up = u + site * (DDEP * CH);
        float uval[DDEP];
        #pragma unroll
        for (int D = 0; D < DDEP; ++D) uval[D] = u_ld(&up[D*CH + ch]);

        float s = 0.f;
        #pragma unroll
        for (int D = 0; D < DDEP; ++D) s += cm[D*8 + d] * uval[D];

        float p = s * s;
        p += __shfl_xor(p, 8); p += __shfl_xor(p, 16); p += __shfl_xor(p, 32);
        if (lane < 8) n2s[wv][lane] = p;
        __syncthreads();
        float n2 = n2s[0][d] + n2s[1][d] + n2s[2][d] + n2s[3][d];
        float v = s * (n2 / (1.f + n2)) / sqrtf(n2 + EPSQ);

        #pragma unroll
        for (int D = 0; D < DDEP; ++D) {
            float q = uval[D] * v;
            q += __shfl_xor(q, 8); q += __shfl_xor(q, 16); q += __shfl_xor(q, 32);
            if (lane < 8) dbs[wv][D][lane] = q;
        }
        __syncthreads();
        if (t < 64) {
            int D = t >> 3, d2 = t & 7;
            brow[t][si] += dbs[0][D][d2] + dbs[1][D][d2] + dbs[2][D][d2] + dbs[3][D][d2];
        }
        __syncthreads();   // brow fully updated before next cm / writeback
    }

    for (int i = t; i < 64 * 47; i += 256) {
        int pl = i / 47, wi = i - pl * 47;
        bws[((size_t)bb*64 + pl)*HW + (size_t)h*WOUT + (w0+wi)] = brow[pl][wi];
    }
}

// ---------------------------------------------------------------------------
// Path A iteration 3: compute s only, write output (coalesced via LDS).
// ---------------------------------------------------------------------------
template<typename UT>
__global__ __launch_bounds__(256) void route_final(
    const UT* __restrict__ u, const float* __restrict__ bws,
    const float* __restrict__ Z, float* __restrict__ out)
{
    const int t = threadIdx.x;
    const int wc = blockIdx.x, h = blockIdx.y, bb = blockIdx.z;
    const int w0 = wc * 47;

    __shared__ float cm[64];
    __shared__ float invZ[8];
    __shared__ float sout[256][47];   // 48 KB

    if (t < 8) invZ[t] = 1.0f / Z[bb * 8 + t];
    __syncthreads();

    const int ch = t, d = ch & 7;
    for (int si = 0; si < 47; ++si) {
        if (t < 64)
            cm[t] = expf(bws[((size_t)bb*64 + t)*HW + (size_t)h*WOUT + (w0+si)]) * invZ[t >> 3];
        __syncthreads();

        size_t site = (size_t)bb * HW + (size_t)h * WOUT + (w0 + si);
        const UT* up = u + site * (DDEP * CH);
        float s = 0.f;
        #pragma unroll
        for (int D = 0; D < DDEP; ++D) s += cm[D*8 + d] * u_ld(&up[D*CH + ch]);
        sout[ch][si] = s;
        __syncthreads();
    }

    for (int i = t; i < 256 * 47; i += 256) {
        int c2 = i / 47, wi = i - c2 * 47;
        out[((size_t)bb*256 + c2)*HW + (size_t)h*WOUT + (w0+wi)] = sout[c2][wi];
    }
}

// ---------------------------------------------------------------------------
// Path B iterations 2/3: recompute conv, fuse routing. FINAL=false: b += db.
// FINAL=true: write s to out (scattered stores, fallback path).
// ---------------------------------------------------------------------------
template<bool FINAL>
__global__ __launch_bounds__(256) void conv_route23(
    const float* __restrict__ x, const float* __restrict__ wconv,
    float* __restrict__ bws, const float* __restrict__ Z, float* __restrict__ out)
{
    const int t  = threadIdx.x;
    const int wx = blockIdx.x, hy = blockIdx.y, bb = blockIdx.z;
    const int h0 = hy * 2, w0 = wx * 2;

    __shared__ float patch[CIN][DDEP][4][4];
    __shared__ float cms[64][4];               // c-coeff per (D*8+d, site)
    __shared__ float n2s[4][8][4];
    __shared__ float dbs[4][8][8][4];
    __shared__ float invZ[8];

    if (t < 8) invZ[t] = 1.0f / Z[bb * 8 + t];
    if (t < 64) {
        #pragma unroll
        for (int s = 0; s < 4; ++s) {
            int sy = s >> 1, sx = s & 1;
            float bv = bws[((size_t)bb*64 + t)*HW + (size_t)(h0+sy)*WOUT + (w0+sx)];
            cms[t][s] = expf(bv);   // scaled by invZ after sync (invZ may not be visible yet)
        }
    }
    // conv_core's __syncthreads() makes patch+cms+invZ visible
    float acc[DDEP][4];
    conv_core(x, wconv, patch, bb, h0, w0, t, acc);

    const int ch = t, d = ch & 7;
    const int lane = t & 63, wv = t >> 6;

    float sv[4], v[4];
    #pragma unroll
    for (int s = 0; s < 4; ++s) {
        float sum = 0.f;
        #pragma unroll
        for (int D = 0; D < DDEP; ++D) sum += cms[D*8 + d][s] * invZ[D] * acc[D][s];
        sv[s] = sum;
    }

    if (FINAL) {
        #pragma unroll
        for (int s = 0; s < 4; ++s) {
            int sy = s >> 1, sx = s & 1;
            out[((size_t)bb*256 + ch)*HW + (size_t)(h0+sy)*WOUT + (w0+sx)] = sv[s];
        }
        return;
    }

    float p[4];
    #pragma unroll
    for (int s = 0; s < 4; ++s) p[s] = sv[s] * sv[s];
    #pragma unroll
    for (int off = 8; off < 64; off <<= 1)
        #pragma unroll
        for (int s = 0; s < 4; ++s) p[s] += __shfl_xor(p[s], off);
    if (lane < 8)
        #pragma unroll
        for (int s = 0; s < 4; ++s) n2s[wv][lane][s] = p[s];
    __syncthreads();
    #pragma unroll
    for (int s = 0; s < 4; ++s) {
        float n2 = n2s[0][d][s] + n2s[1][d][s] + n2s[2][d][s] + n2s[3][d][s];
        v[s] = sv[s] * (n2 / (1.f + n2)) / sqrtf(n2 + EPSQ);
    }
    #pragma unroll
    for (int D = 0; D < DDEP; ++D) {
        float q[4];
        #pragma unroll
        for (int s = 0; s < 4; ++s) q[s] = acc[D][s] * v[s];
        #pragma unroll
        for (int off = 8; off < 64; off <<= 1)
            #pragma unroll
            for (int s = 0; s < 4; ++s) q[s] += __shfl_xor(q[s], off);
        if (lane < 8)
            #pragma unroll
            for (int s = 0; s < 4; ++s) dbs[wv][D][lane][s] = q[s];
    }
    __syncthreads();
    {
        int D = t >> 5, d2 = (t >> 2) & 7, s = t & 3;
        int sy = s >> 1, sx = s & 1;
        float db = dbs[0][D][d2][s] + dbs[1][D][d2][s] + dbs[2][D][d2][s] + dbs[3][D][d2][s];
        size_t idx = ((size_t)(bb*DDEP + D)*DCAP + d2)*HW + (size_t)(h0+sy)*WOUT + (w0+sx);
        bws[idx] += db;   // this thread owns idx exclusively
    }
}

// ---------------------------------------------------------------------------
extern "C" void kernel_launch(void* const* d_in, const int* in_sizes, int n_in,
                              void* d_out, int out_size, void* d_ws, size_t ws_size,
                              hipStream_t stream)
{
    (void)in_sizes; (void)n_in; (void)out_size;
    const float* x     = (const float*)d_in[0];
    const float* wconv = (const float*)d_in[1];
    float* out = (float*)d_out;

    float* bws = (float*)d_ws;
    float* Z   = bws + B_ELEMS;
    void*  ur  = (void*)(Z + 64);
    const size_t base = (B_ELEMS + 64) * sizeof(float);

    if (ws_size >= base + U_ELEMS * sizeof(ushort)) {
        // Path A: u materialized as bf16
        ushort* u = (ushort*)ur;
        conv_iter1<ushort, true><<<dim3(47,47,8), 256, 0, stream>>>(x, wconv, u, bws);
        softmax_z<<<64, 256, 0, stream>>>(bws, Z);
        route_iter<ushort><<<dim3(2,94,8), 256, 0, stream>>>(u, bws, Z);
        softmax_z<<<64, 256, 0, stream>>>(bws, Z);
        route_final<ushort><<<dim3(2,94,8), 256, 0, stream>>>(u, bws, Z, out);
    } else {
        // Path B: recompute conv each iteration (needs only 18.1 MB ws)
        conv_iter1<ushort, false><<<dim3(47,47,8), 256, 0, stream>>>(x, wconv, (ushort*)nullptr, bws);
        softmax_z<<<64, 256, 0, stream>>>(bws, Z);
        conv_route23<false><<<dim3(47,47,8), 256, 0, stream>>>(x, wconv, bws, Z, out);
        softmax_z<<<64, 256, 0, stream>>>(bws, Z);
        conv_route23<true ><<<dim3(47,47,8), 256, 0, stream>>>(x, wconv, bws, Z, out);
    }
}

// Round 3
// 2492.665 us; speedup vs baseline: 1.0329x; 1.0329x over previous
//
#include <hip/hip_runtime.h>
#include <hip/hip_bf16.h>
#include <math.h>

#define BATCH 8
#define CIN   16
#define DDEP  8      // conv spatial depth (routing "D")
#define HIN   96
#define WIN   96
#define HOUT  94
#define WOUT  94
#define HW    (HOUT*WOUT)        // 8836
#define CH    256                 // conv out channels = c*8+d
#define DCAP  8
#define KTOT  (CIN*9)             // 144
#define EPSQ  1e-8f

#define B_ELEMS ((size_t)BATCH*DDEP*DCAP*HW)   // 4,521,984? no: 8*8*8*8836 = 4,524,032 floats
#define U_ELEMS ((size_t)BATCH*HW*DDEP*CH)     // 144,769,024 elems

// ---------- u storage helpers (float or bf16-as-ushort) ----------
__device__ __forceinline__ float u_ld(const ushort* p){ return __bfloat162float(*(const __hip_bfloat16*)p); }
__device__ __forceinline__ float u_ld(const float*  p){ return *p; }
__device__ __forceinline__ void  u_st(ushort* p, float v){ *(__hip_bfloat16*)p = __float2bfloat16(v); }
__device__ __forceinline__ void  u_st(float*  p, float v){ *p = v; }

// ---------------------------------------------------------------------------
// Weight transpose: w[ch][k] -> w_t[k][ch]  (k = ci*9 + kh*3 + kw), 147 KB.
// ---------------------------------------------------------------------------
__global__ __launch_bounds__(256) void transpose_w(
    const float* __restrict__ w, float* __restrict__ w_t)
{
    int k = blockIdx.x;            // 0..143
    int ch = threadIdx.x;          // 0..255
    w_t[(size_t)k * CH + ch] = w[(size_t)ch * KTOT + k];
}

// ---------- conv core: 2x2 (h,w) tile, all D, one thread per out channel ----
// Weights read from w_t (coalesced). Contains one __syncthreads().
__device__ __forceinline__ void conv_core(
    const float* __restrict__ x, const float* __restrict__ wt,
    float (*patch)[DDEP][4][4], int bb, int h0, int w0, int t,
    float acc[DDEP][4])
{
    // stage x patch: 16*8*4*4 = 2048 floats
    #pragma unroll
    for (int k = 0; k < 8; ++k) {
        int i  = t + 256 * k;
        int ci = i >> 7, rem = i & 127;
        int D  = rem >> 4, y = (rem >> 2) & 3, xx = rem & 3;
        patch[ci][D][y][xx] =
            x[(((size_t)(bb * CIN + ci) * DDEP + D) * HIN + (h0 + y)) * WIN + (w0 + xx)];
    }
    __syncthreads();

    #pragma unroll
    for (int D = 0; D < DDEP; ++D)
        #pragma unroll
        for (int s = 0; s < 4; ++s) acc[D][s] = 0.f;

    for (int ci = 0; ci < CIN; ++ci) {
        float wg[9];
        #pragma unroll
        for (int j = 0; j < 9; ++j) wg[j] = wt[(size_t)(ci * 9 + j) * CH + t];
        #pragma unroll
        for (int D = 0; D < DDEP; ++D) {
            const float* pr = &patch[ci][D][0][0];
            float4 r0 = ((const float4*)pr)[0];
            float4 r1 = ((const float4*)pr)[1];
            float4 r2 = ((const float4*)pr)[2];
            float4 r3 = ((const float4*)pr)[3];
            float rr[4][4] = {
                {r0.x,r0.y,r0.z,r0.w},{r1.x,r1.y,r1.z,r1.w},
                {r2.x,r2.y,r2.z,r2.w},{r3.x,r3.y,r3.z,r3.w}};
            #pragma unroll
            for (int sy = 0; sy < 2; ++sy)
                #pragma unroll
                for (int sx = 0; sx < 2; ++sx) {
                    float a = acc[D][sy*2+sx];
                    #pragma unroll
                    for (int kh = 0; kh < 3; ++kh)
                        #pragma unroll
                        for (int kw = 0; kw < 3; ++kw)
                            a += rr[sy+kh][sx+kw] * wg[kh*3+kw];
                    acc[D][sy*2+sx] = a;
                }
        }
    }
}

// ---------------------------------------------------------------------------
// Kernel: conv + routing iteration 1 (c uniform = 1/70688). Optionally writes
// u (layout [site][D][ch]) in storage type UT. Writes b1.
// ---------------------------------------------------------------------------
template<typename UT, bool STOREU>
__global__ __launch_bounds__(256, 2) void conv_iter1(
    const float* __restrict__ x, const float* __restrict__ wt,
    UT* __restrict__ u, float* __restrict__ bws)
{
    const int t  = threadIdx.x;
    const int wx = blockIdx.x, hy = blockIdx.y, bb = blockIdx.z;
    const int h0 = hy * 2, w0 = wx * 2;

    __shared__ float patch[CIN][DDEP][4][4];   // 8 KB
    __shared__ float n2s[4][8][4];             // [wave][d][site]
    __shared__ float dbs[4][8][8][4];          // [wave][D][d][site]

    float acc[DDEP][4];
    conv_core(x, wt, patch, bb, h0, w0, t, acc);

    const int ch = t;
    if (STOREU) {
        #pragma unroll
        for (int sy = 0; sy < 2; ++sy)
            #pragma unroll
            for (int sx = 0; sx < 2; ++sx) {
                size_t site = (size_t)bb * HW + (size_t)(h0+sy) * WOUT + (w0+sx);
                UT* up = u + site * (DDEP * CH);
                #pragma unroll
                for (int D = 0; D < DDEP; ++D) u_st(&up[D*CH + ch], acc[D][sy*2+sx]);
            }
    }

    const int d = ch & 7;
    const int lane = t & 63, wv = t >> 6;
    const float inv = 1.0f / (float)(DCAP * HW);

    float s1[4], v[4];
    #pragma unroll
    for (int s = 0; s < 4; ++s) {
        float sum = 0.f;
        #pragma unroll
        for (int D = 0; D < DDEP; ++D) sum += acc[D][s];
        s1[s] = sum * inv;
    }
    float p[4];
    #pragma unroll
    for (int s = 0; s < 4; ++s) p[s] = s1[s] * s1[s];
    #pragma unroll
    for (int off = 8; off < 64; off <<= 1)
        #pragma unroll
        for (int s = 0; s < 4; ++s) p[s] += __shfl_xor(p[s], off);
    if (lane < 8)
        #pragma unroll
        for (int s = 0; s < 4; ++s) n2s[wv][lane][s] = p[s];
    __syncthreads();
    #pragma unroll
    for (int s = 0; s < 4; ++s) {
        float n2 = n2s[0][d][s] + n2s[1][d][s] + n2s[2][d][s] + n2s[3][d][s];
        v[s] = s1[s] * (n2 / (1.f + n2)) / sqrtf(n2 + EPSQ);
    }
    #pragma unroll
    for (int D = 0; D < DDEP; ++D) {
        float q[4];
        #pragma unroll
        for (int s = 0; s < 4; ++s) q[s] = acc[D][s] * v[s];
        #pragma unroll
        for (int off = 8; off < 64; off <<= 1)
            #pragma unroll
            for (int s = 0; s < 4; ++s) q[s] += __shfl_xor(q[s], off);
        if (lane < 8)
            #pragma unroll
            for (int s = 0; s < 4; ++s) dbs[wv][D][lane][s] = q[s];
    }
    __syncthreads();
    if (t < 128) {
        int D = t >> 4, d2 = (t >> 1) & 7, sy = t & 1;
        float2 v2;
        v2.x = dbs[0][D][d2][sy*2+0] + dbs[1][D][d2][sy*2+0]
             + dbs[2][D][d2][sy*2+0] + dbs[3][D][d2][sy*2+0];
        v2.y = dbs[0][D][d2][sy*2+1] + dbs[1][D][d2][sy*2+1]
             + dbs[2][D][d2][sy*2+1] + dbs[3][D][d2][sy*2+1];
        *(float2*)&bws[((size_t)(bb*DDEP + D)*DCAP + d2)*HW + (size_t)(h0+sy)*WOUT + w0] = v2;
    }
}

// ---------------------------------------------------------------------------
// Z[B,D] = sum over (d,h,w) of exp(b). 64 blocks, one per (B,D).
// ---------------------------------------------------------------------------
__global__ __launch_bounds__(256) void softmax_z(
    const float* __restrict__ bws, float* __restrict__ Z)
{
    const int bd = blockIdx.x;
    const float* p = bws + (size_t)bd * (DCAP * HW);
    float sum = 0.f;
    for (int i = threadIdx.x; i < DCAP * HW; i += 256) sum += expf(p[i]);
    #pragma unroll
    for (int off = 1; off < 64; off <<= 1) sum += __shfl_xor(sum, off);
    __shared__ float ps[4];
    if ((threadIdx.x & 63) == 0) ps[threadIdx.x >> 6] = sum;
    __syncthreads();
    if (threadIdx.x == 0) Z[bd] = ps[0] + ps[1] + ps[2] + ps[3];
}

// ---------------------------------------------------------------------------
// Path A iteration 2: one pass over stored u, b += db in place.
// ---------------------------------------------------------------------------
template<typename UT>
__global__ __launch_bounds__(256) void route_iter(
    const UT* __restrict__ u, float* __restrict__ bws, const float* __restrict__ Z)
{
    const int t = threadIdx.x, lane = t & 63, wv = t >> 6;
    const int wc = blockIdx.x, h = blockIdx.y, bb = blockIdx.z;
    const int w0 = wc * 47;

    __shared__ float brow[64][47];
    __shared__ float cm[64];
    __shared__ float n2s[4][8];
    __shared__ float dbs[4][8][8];
    __shared__ float invZ[8];

    if (t < 8) invZ[t] = 1.0f / Z[bb * 8 + t];
    for (int i = t; i < 64 * 47; i += 256) {
        int pl = i / 47, wi = i - pl * 47;
        brow[pl][wi] = bws[((size_t)bb*64 + pl)*HW + (size_t)h*WOUT + (w0+wi)];
    }
    __syncthreads();

    const int ch = t, d = ch & 7;
    for (int si = 0; si < 47; ++si) {
        if (t < 64) cm[t] = expf(brow[t][si]) * invZ[t >> 3];
        __syncthreads();

        size_t site = (size_t)bb * HW + (size_t)h * WOUT + (w0 + si);
        const UT* up = u + site * (DDEP * CH);
        float uval[DDEP];
        #pragma unroll
        for (int D = 0; D < DDEP; ++D) uval[D] = u_ld(&up[D*CH + ch]);

        float s = 0.f;
        #pragma unroll
        for (int D = 0; D < DDEP; ++D) s += cm[D*8 + d] * uval[D];

        float p = s * s;
        p += __shfl_xor(p, 8); p += __shfl_xor(p, 16); p += __shfl_xor(p, 32);
        if (lane < 8) n2s[wv][lane] = p;
        __syncthreads();
        float n2 = n2s[0][d] + n2s[1][d] + n2s[2][d] + n2s[3][d];
        float v = s * (n2 / (1.f + n2)) / sqrtf(n2 + EPSQ);

        #pragma unroll
        for (int D = 0; D < DDEP; ++D) {
            float q = uval[D] * v;
            q += __shfl_xor(q, 8); q += __shfl_xor(q, 16); q += __shfl_xor(q, 32);
            if (lane < 8) dbs[wv][D][lane] = q;
        }
        __syncthreads();
        if (t < 64) {
            int D = t >> 3, d2 = t & 7;
            brow[t][si] += dbs[0][D][d2] + dbs[1][D][d2] + dbs[2][D][d2] + dbs[3][D][d2];
        }
        __syncthreads();
    }

    for (int i = t; i < 64 * 47; i += 256) {
        int pl = i / 47, wi = i - pl * 47;
        bws[((size_t)bb*64 + pl)*HW + (size_t)h*WOUT + (w0+wi)] = brow[pl][wi];
    }
}

// ---------------------------------------------------------------------------
// Path A iteration 3: compute s only, write output (coalesced via LDS).
// ---------------------------------------------------------------------------
template<typename UT>
__global__ __launch_bounds__(256) void route_final(
    const UT* __restrict__ u, const float* __restrict__ bws,
    const float* __restrict__ Z, float* __restrict__ out)
{
    const int t = threadIdx.x;
    const int wc = blockIdx.x, h = blockIdx.y, bb = blockIdx.z;
    const int w0 = wc * 47;

    __shared__ float cm[64];
    __shared__ float invZ[8];
    __shared__ float sout[256][47];   // 48 KB

    if (t < 8) invZ[t] = 1.0f / Z[bb * 8 + t];
    __syncthreads();

    const int ch = t, d = ch & 7;
    for (int si = 0; si < 47; ++si) {
        if (t < 64)
            cm[t] = expf(bws[((size_t)bb*64 + t)*HW + (size_t)h*WOUT + (w0+si)]) * invZ[t >> 3];
        __syncthreads();

        size_t site = (size_t)bb * HW + (size_t)h * WOUT + (w0 + si);
        const UT* up = u + site * (DDEP * CH);
        float s = 0.f;
        #pragma unroll
        for (int D = 0; D < DDEP; ++D) s += cm[D*8 + d] * u_ld(&up[D*CH + ch]);
        sout[ch][si] = s;
        __syncthreads();
    }

    for (int i = t; i < 256 * 47; i += 256) {
        int c2 = i / 47, wi = i - c2 * 47;
        out[((size_t)bb*256 + c2)*HW + (size_t)h*WOUT + (w0+wi)] = sout[c2][wi];
    }
}

// ---------------------------------------------------------------------------
// Path B iterations 2/3: recompute conv, fuse routing. FINAL=false: b += db.
// FINAL=true: write s to out (LDS-staged float2 stores).
// ---------------------------------------------------------------------------
template<bool FINAL>
__global__ __launch_bounds__(256, 2) void conv_route23(
    const float* __restrict__ x, const float* __restrict__ wt,
    float* __restrict__ bws, const float* __restrict__ Z, float* __restrict__ out)
{
    const int t  = threadIdx.x;
    const int wx = blockIdx.x, hy = blockIdx.y, bb = blockIdx.z;
    const int h0 = hy * 2, w0 = wx * 2;

    __shared__ float patch[CIN][DDEP][4][4];
    __shared__ float cms[64][4];               // c-coeff per (D*8+d, site)
    __shared__ float n2s[4][8][4];
    __shared__ float dbs[4][8][8][4];          // (FINAL: reused as sout[256][4])
    __shared__ float invZ[8];

    if (t < 8) invZ[t] = 1.0f / Z[bb * 8 + t];
    if (t < 64) {
        #pragma unroll
        for (int s = 0; s < 4; ++s) {
            int sy = s >> 1, sx = s & 1;
            float bv = bws[((size_t)bb*64 + t)*HW + (size_t)(h0+sy)*WOUT + (w0+sx)];
            cms[t][s] = expf(bv);   // scaled by invZ after conv_core's barrier
        }
    }
    float acc[DDEP][4];
    conv_core(x, wt, patch, bb, h0, w0, t, acc);   // barrier makes cms/invZ visible

    const int ch = t, d = ch & 7;
    const int lane = t & 63, wv = t >> 6;

    float sv[4], v[4];
    #pragma unroll
    for (int s = 0; s < 4; ++s) {
        float sum = 0.f;
        #pragma unroll
        for (int D = 0; D < DDEP; ++D) sum += cms[D*8 + d][s] * invZ[D] * acc[D][s];
        sv[s] = sum;
    }

    if (FINAL) {
        float* sout = &dbs[0][0][0][0];        // 256*4 floats
        #pragma unroll
        for (int s = 0; s < 4; ++s) sout[ch*4 + s] = sv[s];
        __syncthreads();
        for (int i = t; i < 512; i += 256) {
            int c2 = i >> 1, sy = i & 1;
            float2 v2;
            v2.x = sout[c2*4 + sy*2 + 0];
            v2.y = sout[c2*4 + sy*2 + 1];
            *(float2*)&out[((size_t)bb*256 + c2)*HW + (size_t)(h0+sy)*WOUT + w0] = v2;
        }
        return;
    }

    float p[4];
    #pragma unroll
    for (int s = 0; s < 4; ++s) p[s] = sv[s] * sv[s];
    #pragma unroll
    for (int off = 8; off < 64; off <<= 1)
        #pragma unroll
        for (int s = 0; s < 4; ++s) p[s] += __shfl_xor(p[s], off);
    if (lane < 8)
        #pragma unroll
        for (int s = 0; s < 4; ++s) n2s[wv][lane][s] = p[s];
    __syncthreads();
    #pragma unroll
    for (int s = 0; s < 4; ++s) {
        float n2 = n2s[0][d][s] + n2s[1][d][s] + n2s[2][d][s] + n2s[3][d][s];
        v[s] = sv[s] * (n2 / (1.f + n2)) / sqrtf(n2 + EPSQ);
    }
    #pragma unroll
    for (int D = 0; D < DDEP; ++D) {
        float q[4];
        #pragma unroll
        for (int s = 0; s < 4; ++s) q[s] = acc[D][s] * v[s];
        #pragma unroll
        for (int off = 8; off < 64; off <<= 1)
            #pragma unroll
            for (int s = 0; s < 4; ++s) q[s] += __shfl_xor(q[s], off);
        if (lane < 8)
            #pragma unroll
            for (int s = 0; s < 4; ++s) dbs[wv][D][lane][s] = q[s];
    }
    __syncthreads();
    if (t < 128) {
        int D = t >> 4, d2 = (t >> 1) & 7, sy = t & 1;
        float2 add;
        add.x = dbs[0][D][d2][sy*2+0] + dbs[1][D][d2][sy*2+0]
              + dbs[2][D][d2][sy*2+0] + dbs[3][D][d2][sy*2+0];
        add.y = dbs[0][D][d2][sy*2+1] + dbs[1][D][d2][sy*2+1]
              + dbs[2][D][d2][sy*2+1] + dbs[3][D][d2][sy*2+1];
        float2* bp = (float2*)&bws[((size_t)(bb*DDEP + D)*DCAP + d2)*HW + (size_t)(h0+sy)*WOUT + w0];
        float2 old = *bp;
        old.x += add.x; old.y += add.y;
        *bp = old;     // this thread owns both elements exclusively
    }
}

// ---------------------------------------------------------------------------
extern "C" void kernel_launch(void* const* d_in, const int* in_sizes, int n_in,
                              void* d_out, int out_size, void* d_ws, size_t ws_size,
                              hipStream_t stream)
{
    (void)in_sizes; (void)n_in; (void)out_size;
    const float* x     = (const float*)d_in[0];
    const float* wconv = (const float*)d_in[1];
    float* out = (float*)d_out;

    float* bws = (float*)d_ws;
    float* Z   = bws + B_ELEMS;
    float* w_t = Z + 64;
    void*  ur  = (void*)(w_t + KTOT * CH);
    const size_t base = (B_ELEMS + 64 + (size_t)KTOT * CH) * sizeof(float);

    transpose_w<<<KTOT, 256, 0, stream>>>(wconv, w_t);

    if (ws_size >= base + U_ELEMS * sizeof(ushort)) {
        // Path A: u materialized as bf16
        ushort* u = (ushort*)ur;
        conv_iter1<ushort, true><<<dim3(47,47,8), 256, 0, stream>>>(x, w_t, u, bws);
        softmax_z<<<64, 256, 0, stream>>>(bws, Z);
        route_iter<ushort><<<dim3(2,94,8), 256, 0, stream>>>(u, bws, Z);
        softmax_z<<<64, 256, 0, stream>>>(bws, Z);
        route_final<ushort><<<dim3(2,94,8), 256, 0, stream>>>(u, bws, Z, out);
    } else {
        // Path B: recompute conv each iteration (needs only ~18.3 MB ws)
        conv_iter1<ushort, false><<<dim3(47,47,8), 256, 0, stream>>>(x, w_t, (ushort*)nullptr, bws);
        softmax_z<<<64, 256, 0, stream>>>(bws, Z);
        conv_route23<false><<<dim3(47,47,8), 256, 0, stream>>>(x, w_t, bws, Z, out);
        softmax_z<<<64, 256, 0, stream>>>(bws, Z);
        conv_route23<true ><<<dim3(47,47,8), 256, 0, stream>>>(x, w_t, bws, Z, out);
    }
}